// Round 4
// baseline (123847.229 us; speedup 1.0000x reference)
//
#include <hip/hip_runtime.h>
#include <stdint.h>

#define TT 8192
#define NN 512
#define MM 2048
#define KK 3
#define RHO_C 1e-4f
#define NWG 256
#define NTHR 512

__device__ __forceinline__ unsigned long long pack_eh(unsigned int e, float v) {
    union { float f; unsigned int u; } c; c.f = v;
    return ((unsigned long long)e << 32) | (unsigned long long)c.u;
}

// Persistent kernel: one WG per CU, WG wg owns rows [8*wg, 8*wg+8).
// Wave w owns row 8*wg+w; lane holds M cols c = lane + 64*cb (cb<32) in regs.
//
// Correctness = R1's gauntlet-proven protocol, unchanged:
//   packed (epoch<<32)|f32 entries, parity double-buffered, relaxed agent
//   atomics, per-thread 4-entry poll with __syncthreads_and rounds.
// Perf layer (hints only, cannot affect correctness):
//   - per-WG monotone epoch flags; wave 0 alone spins on all 256 flags
//     (>= compare: monotone, deadlock-free; 0xAA poison passes harmlessly),
//     relays via monotone LDS `ready` word. Cuts per-round fabric polling
//     from 16KB x 8 waves to 1KB x 1 wave per WG.
//   - entry order rotated by wg so WGs don't sweep cachelines in lockstep.
__global__ __launch_bounds__(NTHR, 2)
void lista_persist(const float* __restrict__ x,      // [T, N]
                   const float* __restrict__ A,      // [K, M, N]
                   const float* __restrict__ alpha,  // [K+1]
                   const float* __restrict__ h0,     // [M]
                   float* __restrict__ out,          // [T, M]
                   unsigned long long* __restrict__ hbuf,  // ws: [2][M] u64
                   unsigned int* __restrict__ flags)       // ws: [NWG] u32
{
    const int wg   = blockIdx.x;
    const int tid  = threadIdx.x;
    const int w    = tid >> 6;
    const int lane = tid & 63;
    const int row  = wg * 8 + w;

    __shared__ float At[4][MM];      // 32 KB (init only)
    __shared__ float Aplds[8][NN];   // 16 KB (init only)
    __shared__ float lds_h[MM];      //  8 KB
    __shared__ float lds_x[NN];      //  2 KB
    __shared__ int   ready;          // monotone epoch relay (wave0 -> all)

    float inva[KK], rhoa[KK];
#pragma unroll
    for (int k = 0; k < KK; ++k) {
        float a = alpha[k + 1];
        inva[k] = 1.0f / a;
        rhoa[k] = RHO_C / a;
    }

    // A'_k row of this wave in regs: a2[k][m] = A[k][row][lane+64m] / a_k
    float a2[KK][8];
#pragma unroll
    for (int k = 0; k < KK; ++k) {
        const float* Ar = A + ((size_t)k * MM + row) * NN;
#pragma unroll
        for (int m = 0; m < 8; ++m) a2[k][m] = Ar[lane + 64 * m] * inva[k];
    }

    // ---------------- init: M_k = I - (A_k A_k^T)/a_k rows into registers ----
    float mr[KK][32];
#pragma unroll
    for (int k = 0; k < KK; ++k)
#pragma unroll
        for (int cb = 0; cb < 32; ++cb) mr[k][cb] = 0.0f;

#pragma unroll
    for (int k = 0; k < KK; ++k) {
#pragma unroll
        for (int m = 0; m < 8; ++m) Aplds[w][lane + 64 * m] = a2[k][m];
        const float* Ak = A + (size_t)k * MM * NN;
        for (int jc = 0; jc < 128; ++jc) {
            __syncthreads();
#pragma unroll
            for (int cc = 0; cc < 4; ++cc) {
                int c = tid + 512 * cc;
                const float4 v = *(const float4*)(Ak + (size_t)c * NN + jc * 4);
                At[0][c] = v.x; At[1][c] = v.y; At[2][c] = v.z; At[3][c] = v.w;
            }
            __syncthreads();
#pragma unroll
            for (int jj = 0; jj < 4; ++jj) {
                float s = Aplds[w][jc * 4 + jj];   // broadcast
#pragma unroll
                for (int cb = 0; cb < 32; ++cb)
                    mr[k][cb] += s * At[jj][lane + 64 * cb];
            }
        }
        __syncthreads();
    }
#pragma unroll
    for (int k = 0; k < KK; ++k)
#pragma unroll
        for (int cb = 0; cb < 32; ++cb) {
            float d = (lane + 64 * cb == row) ? 1.0f : 0.0f;
            mr[k][cb] = d - mr[k][cb];
        }

    // ---------------- prologue: publish h0 as epoch 0 ----------------
    if (tid == 0) ready = 0;
    if (lane == 0)
        __hip_atomic_store(&hbuf[row], pack_eh(0u, h0[row]),
                           __ATOMIC_RELAXED, __HIP_MEMORY_SCOPE_AGENT);
    __syncthreads();

    const unsigned long long* fl64 = (const unsigned long long*)flags;

    // ---------------- sequential scan ----------------
    unsigned int e = 0;   // epoch of the state consumed by the next matvec
    for (int t = 0; t < TT; ++t) {
        lds_x[tid] = x[(size_t)t * NN + tid];   // prior reads done (body-end barrier)
#pragma unroll
        for (int k = 0; k < KK; ++k) {
            // --- gate (hint): wave 0 spins on 256 monotone flags, relays ---
            if (w == 0) {
                bool g;
                do {
                    unsigned long long f0 = __hip_atomic_load(&fl64[lane],
                        __ATOMIC_RELAXED, __HIP_MEMORY_SCOPE_AGENT);
                    unsigned long long f1 = __hip_atomic_load(&fl64[lane + 64],
                        __ATOMIC_RELAXED, __HIP_MEMORY_SCOPE_AGENT);
                    g = ((unsigned int)f0 >= e) & ((unsigned int)(f0 >> 32) >= e)
                      & ((unsigned int)f1 >= e) & ((unsigned int)(f1 >> 32) >= e);
                } while (!__all(g));
                if (lane == 0)
                    __hip_atomic_store(&ready, (int)e,
                                       __ATOMIC_RELAXED, __HIP_MEMORY_SCOPE_WORKGROUP);
            }
            while (__hip_atomic_load(&ready, __ATOMIC_RELAXED,
                                     __HIP_MEMORY_SCOPE_WORKGROUP) < (int)e) {}

            // --- tag poll (R1 protocol, authoritative), rotated entry order ---
            const unsigned long long* src = hbuf + (size_t)(e & 1) * MM;
            const int base = (tid + wg) & 511;
            bool ok0 = false, ok1 = false, ok2 = false, ok3 = false;
            int done;
            do {
                int all = 1;
                if (!ok0) {
                    unsigned long long v = __hip_atomic_load(&src[base],
                        __ATOMIC_RELAXED, __HIP_MEMORY_SCOPE_AGENT);
                    if ((unsigned int)(v >> 32) == e) {
                        lds_h[base] = __uint_as_float((unsigned int)v); ok0 = true;
                    } else all = 0;
                }
                if (!ok1) {
                    unsigned long long v = __hip_atomic_load(&src[base + 512],
                        __ATOMIC_RELAXED, __HIP_MEMORY_SCOPE_AGENT);
                    if ((unsigned int)(v >> 32) == e) {
                        lds_h[base + 512] = __uint_as_float((unsigned int)v); ok1 = true;
                    } else all = 0;
                }
                if (!ok2) {
                    unsigned long long v = __hip_atomic_load(&src[base + 1024],
                        __ATOMIC_RELAXED, __HIP_MEMORY_SCOPE_AGENT);
                    if ((unsigned int)(v >> 32) == e) {
                        lds_h[base + 1024] = __uint_as_float((unsigned int)v); ok2 = true;
                    } else all = 0;
                }
                if (!ok3) {
                    unsigned long long v = __hip_atomic_load(&src[base + 1536],
                        __ATOMIC_RELAXED, __HIP_MEMORY_SCOPE_AGENT);
                    if ((unsigned int)(v >> 32) == e) {
                        lds_h[base + 1536] = __uint_as_float((unsigned int)v); ok3 = true;
                    } else all = 0;
                }
                done = __syncthreads_and(all);
            } while (!done);   // barrier-AND also orders lds_h/lds_x for compute

            // --- compute: v = M_k[row,:] @ h + (A_k[row,:]/a) @ x_t ---
            float p = 0.0f;
#pragma unroll
            for (int m = 0; m < 8; ++m)  p += a2[k][m] * lds_x[lane + 64 * m];
#pragma unroll
            for (int cb = 0; cb < 32; ++cb) p += mr[k][cb] * lds_h[lane + 64 * cb];
#pragma unroll
            for (int s = 1; s < 64; s <<= 1) p += __shfl_xor(p, s, 64);
            float hn = fmaxf(p - rhoa[k], 0.0f);

            // --- publish epoch e+1 ---
            ++e;
            if (lane == 0) {
                __hip_atomic_store(&hbuf[(size_t)(e & 1) * MM + row], pack_eh(e, hn),
                                   __ATOMIC_RELAXED, __HIP_MEMORY_SCOPE_AGENT);
                if (k == KK - 1) out[(size_t)t * MM + row] = hn;
            }
            __syncthreads();   // all waves published e; all lds reads done
            if (tid == 0)
                __hip_atomic_store(&flags[wg], e,
                                   __ATOMIC_RELAXED, __HIP_MEMORY_SCOPE_AGENT);
        }
    }
}

extern "C" void kernel_launch(void* const* d_in, const int* in_sizes, int n_in,
                              void* d_out, int out_size, void* d_ws, size_t ws_size,
                              hipStream_t stream) {
    const float* x     = (const float*)d_in[0];
    const float* A     = (const float*)d_in[1];
    const float* alpha = (const float*)d_in[2];
    const float* h0    = (const float*)d_in[3];
    float* out = (float*)d_out;
    unsigned long long* hbuf = (unsigned long long*)d_ws;           // 32 KB
    unsigned int* flags = (unsigned int*)((char*)d_ws + 2 * MM * sizeof(unsigned long long));

    hipLaunchKernelGGL(lista_persist, dim3(NWG), dim3(NTHR), 0, stream,
                       x, A, alpha, h0, out, hbuf, flags);
}

// Round 5
// 76375.049 us; speedup vs baseline: 1.6216x; 1.6216x over previous
//
#include <hip/hip_runtime.h>
#include <stdint.h>

#define TT 8192
#define NN 512
#define MM 2048
#define KK 3
#define RHO_C 1e-4f
#define NWG 256
#define NTHR 512
#define NCHUNK (NWG * 3)   // 768 16B chunks per parity buffer

typedef unsigned int u32x4 __attribute__((ext_vector_type(4)));

// Persistent kernel: one WG per CU, WG wg owns rows [8*wg, 8*wg+8).
// Wave w owns row 8*wg+w; lane holds M cols c = lane + 64*cb (cb<32) in regs.
//
// Protocol = R1's proven parity/epoch-tag scheme; transport reformatted:
//   per WG record = 3 chunks of 16B {u32 epoch, f32 v0, f32 v1, f32 v2}
//   (8 h-values + pad), written with global_store_dwordx4 sc0 sc1 (coherent,
//   bypasses L1/L2 -> visible cross-XCD), read with global_load_dwordx4
//   sc0 sc1. 16B aligned accesses are single line-granular transactions =>
//   a chunk reads entirely-old or entirely-new; the embedded tag makes both
//   safe. Tag in [1, 24576]; ws poison 0xAAAAAAAA never matches.
//   Chunk tag during poll-for-e is in {e-2, e} (same induction as R1), so
//   re-reading an already-fresh chunk is benign (same value).
__global__ __launch_bounds__(NTHR, 2)
void lista_persist(const float* __restrict__ x,      // [T, N]
                   const float* __restrict__ A,      // [K, M, N]
                   const float* __restrict__ alpha,  // [K+1]
                   const float* __restrict__ h0,     // [M]
                   float* __restrict__ out,          // [T, M]
                   u32x4* __restrict__ hbuf)         // ws: [2][NCHUNK] 16B
{
    const int wg   = blockIdx.x;
    const int tid  = threadIdx.x;
    const int w    = tid >> 6;
    const int lane = tid & 63;
    const int row  = wg * 8 + w;

    __shared__ float At[4][MM];      // 32 KB (init only)
    __shared__ float Aplds[8][NN];   // 16 KB (init only)
    __shared__ float lds_h[MM];      //  8 KB
    __shared__ float lds_x[NN];      //  2 KB
    __shared__ float lds_hv[8];      // this WG's 8 new h-values

    float inva[KK], rhoa[KK];
#pragma unroll
    for (int k = 0; k < KK; ++k) {
        float a = alpha[k + 1];
        inva[k] = 1.0f / a;
        rhoa[k] = RHO_C / a;
    }

    // A'_k row of this wave in regs: a2[k][m] = A[k][row][lane+64m] / a_k
    float a2[KK][8];
#pragma unroll
    for (int k = 0; k < KK; ++k) {
        const float* Ar = A + ((size_t)k * MM + row) * NN;
#pragma unroll
        for (int m = 0; m < 8; ++m) a2[k][m] = Ar[lane + 64 * m] * inva[k];
    }

    // ---------------- init: M_k = I - (A_k A_k^T)/a_k rows into registers ----
    float mr[KK][32];
#pragma unroll
    for (int k = 0; k < KK; ++k)
#pragma unroll
        for (int cb = 0; cb < 32; ++cb) mr[k][cb] = 0.0f;

#pragma unroll
    for (int k = 0; k < KK; ++k) {
#pragma unroll
        for (int m = 0; m < 8; ++m) Aplds[w][lane + 64 * m] = a2[k][m];
        const float* Ak = A + (size_t)k * MM * NN;
        for (int jc = 0; jc < 128; ++jc) {
            __syncthreads();
#pragma unroll
            for (int cc = 0; cc < 4; ++cc) {
                int c = tid + 512 * cc;
                const float4 v = *(const float4*)(Ak + (size_t)c * NN + jc * 4);
                At[0][c] = v.x; At[1][c] = v.y; At[2][c] = v.z; At[3][c] = v.w;
            }
            __syncthreads();
#pragma unroll
            for (int jj = 0; jj < 4; ++jj) {
                float s = Aplds[w][jc * 4 + jj];   // broadcast
#pragma unroll
                for (int cb = 0; cb < 32; ++cb)
                    mr[k][cb] += s * At[jj][lane + 64 * cb];
            }
        }
        __syncthreads();
    }
#pragma unroll
    for (int k = 0; k < KK; ++k)
#pragma unroll
        for (int cb = 0; cb < 32; ++cb) {
            float d = (lane + 64 * cb == row) ? 1.0f : 0.0f;
            mr[k][cb] = d - mr[k][cb];
        }

    // consumer chunk ownership: thread tid polls chunk tid (all) and
    // chunk 512+tid (tid<256). chunk c -> record c/3, part c%3,
    // h rows [rec*8 + part*3, +3) (part 2 carries only 2 values).
    const int  cA   = tid;
    const int  recA = cA / 3, partA = cA % 3;
    const int  rowA = recA * 8 + partA * 3;
    const bool hasB = (tid < 256);
    const int  cB   = 512 + tid;
    const int  recB = cB / 3, partB = cB % 3;
    const int  rowB = recB * 8 + partB * 3;

    // ---------------- prologue: epoch-0 state straight from inputs ----------
#pragma unroll
    for (int j = 0; j < 4; ++j) lds_h[tid + 512 * j] = h0[tid + 512 * j];
    lds_x[tid] = x[tid];
    __syncthreads();

    // ---------------- sequential scan ----------------
    unsigned int e = 0;   // epoch of the state in lds_h
    for (int t = 0; t < TT; ++t) {
#pragma unroll
        for (int k = 0; k < KK; ++k) {
            // --- compute: v = M_k[row,:] @ h + (A_k[row,:]/a) @ x_t ---
            float p = 0.0f;
#pragma unroll
            for (int m = 0; m < 8; ++m)  p += a2[k][m] * lds_x[lane + 64 * m];
#pragma unroll
            for (int cb = 0; cb < 32; ++cb) p += mr[k][cb] * lds_h[lane + 64 * cb];
#pragma unroll
            for (int s = 1; s < 64; s <<= 1) p += __shfl_xor(p, s, 64);
            float hn = fmaxf(p - rhoa[k], 0.0f);

            // --- publish epoch e+1 ---
            ++e;
            if (lane == 0) {
                lds_hv[w] = hn;
                if (k == KK - 1) out[(size_t)t * MM + row] = hn;
            }
            __syncthreads();   // lds_hv ready; all lds_h/lds_x reads done
            if (tid < 3) {
                const int base = tid * 3;
                u32x4 ch;
                ch.x = e;
                ch.y = __float_as_uint(lds_hv[base]);
                ch.z = __float_as_uint(lds_hv[base + 1]);
                ch.w = (tid < 2) ? __float_as_uint(lds_hv[base + 2]) : 0u;
                u32x4* dst = hbuf + (size_t)(e & 1) * NCHUNK + (wg * 3 + tid);
                asm volatile("global_store_dwordx4 %0, %1, off sc0 sc1"
                             :: "v"(dst), "v"(ch) : "memory");
            }
            // stage x_{t+1}: load latency overlaps the poll's remote wait
            if (k == KK - 1 && t + 1 < TT)
                lds_x[tid] = x[(size_t)(t + 1) * NN + tid];

            // --- poll for state e (barrier-AND rounds, R1 structure) ---
            const u32x4* src = hbuf + (size_t)(e & 1) * NCHUNK;
            bool okA = false, okB = !hasB;
            int done;
            do {
                u32x4 ra;
                if (hasB) {
                    u32x4 rb;
                    asm volatile(
                        "global_load_dwordx4 %0, %2, off sc0 sc1\n\t"
                        "global_load_dwordx4 %1, %3, off sc0 sc1\n\t"
                        "s_waitcnt vmcnt(0)"
                        : "=v"(ra), "=v"(rb)
                        : "v"(src + cA), "v"(src + cB)
                        : "memory");
                    if (rb.x == e) {
                        lds_h[rowB]     = __uint_as_float(rb.y);
                        lds_h[rowB + 1] = __uint_as_float(rb.z);
                        if (partB < 2) lds_h[rowB + 2] = __uint_as_float(rb.w);
                        okB = true;
                    }
                } else {
                    asm volatile(
                        "global_load_dwordx4 %0, %1, off sc0 sc1\n\t"
                        "s_waitcnt vmcnt(0)"
                        : "=v"(ra)
                        : "v"(src + cA)
                        : "memory");
                }
                if (ra.x == e) {
                    lds_h[rowA]     = __uint_as_float(ra.y);
                    lds_h[rowA + 1] = __uint_as_float(ra.z);
                    if (partA < 2) lds_h[rowA + 2] = __uint_as_float(ra.w);
                    okA = true;
                }
                done = __syncthreads_and(okA & okB);
            } while (!done);   // barrier also orders lds_h/lds_x for compute
        }
    }
}

extern "C" void kernel_launch(void* const* d_in, const int* in_sizes, int n_in,
                              void* d_out, int out_size, void* d_ws, size_t ws_size,
                              hipStream_t stream) {
    const float* x     = (const float*)d_in[0];
    const float* A     = (const float*)d_in[1];
    const float* alpha = (const float*)d_in[2];
    const float* h0    = (const float*)d_in[3];
    float* out = (float*)d_out;
    u32x4* hbuf = (u32x4*)d_ws;   // 2 * 768 * 16B = 24 KB

    hipLaunchKernelGGL(lista_persist, dim3(NWG), dim3(NTHR), 0, stream,
                       x, A, alpha, h0, out, hbuf);
}

// Round 6
// 60798.578 us; speedup vs baseline: 2.0370x; 1.2562x over previous
//
#include <hip/hip_runtime.h>
#include <stdint.h>

#define TT 8192
#define NN 512
#define MM 2048
#define KK 3
#define RHO_C 1e-4f
#define NWG 256
#define NTHR 512
#define NCHUNK (NWG * 3)   // 768 16B chunks per parity buffer

typedef unsigned int u32x4 __attribute__((ext_vector_type(4)));

// Persistent kernel: one WG per CU, WG wg owns rows [8*wg, 8*wg+8).
// Wave w owns row 8*wg+w; lane holds M cols c = lane + 64*cb (cb<32) in regs.
//
// Protocol (R5, gauntlet-proven): per WG record = 3 x 16B chunks
//   {u32 epoch, f32 v0, f32 v1, f32 v2}, stored with global_store_dwordx4
//   sc0 sc1 after the publish barrier B1; consumers load with
//   global_load_dwordx4 sc0 sc1 (16B line-granular => chunk is entirely-old
//   or entirely-new; tag makes both safe). During poll-for-e a chunk's tag
//   is in {e-2, e} (parity induction), so re-reading/re-writing a fresh
//   chunk is idempotent. Poison 0xAAAAAAAA never matches a real tag.
// R6 change: poll is wave-synchronous free-running (__all exit), no WG
//   barrier per round; single trailing __syncthreads (B2). B1 orders all
//   lds_h reads before spin writes; B2 orders spin writes before reads.
__global__ __launch_bounds__(NTHR, 2)
void lista_persist(const float* __restrict__ x,      // [T, N]
                   const float* __restrict__ A,      // [K, M, N]
                   const float* __restrict__ alpha,  // [K+1]
                   const float* __restrict__ h0,     // [M]
                   float* __restrict__ out,          // [T, M]
                   u32x4* __restrict__ hbuf)         // ws: [2][NCHUNK] 16B
{
    const int wg   = blockIdx.x;
    const int tid  = threadIdx.x;
    const int w    = tid >> 6;
    const int lane = tid & 63;
    const int row  = wg * 8 + w;

    __shared__ float At[4][MM];      // 32 KB (init only)
    __shared__ float Aplds[8][NN];   // 16 KB (init only)
    __shared__ float lds_h[MM];      //  8 KB
    __shared__ float lds_x[NN];      //  2 KB
    __shared__ float lds_hv[8];      // this WG's 8 new h-values

    float inva[KK], rhoa[KK];
#pragma unroll
    for (int k = 0; k < KK; ++k) {
        float a = alpha[k + 1];
        inva[k] = 1.0f / a;
        rhoa[k] = RHO_C / a;
    }

    // A'_k row of this wave in regs: a2[k][m] = A[k][row][lane+64m] / a_k
    float a2[KK][8];
#pragma unroll
    for (int k = 0; k < KK; ++k) {
        const float* Ar = A + ((size_t)k * MM + row) * NN;
#pragma unroll
        for (int m = 0; m < 8; ++m) a2[k][m] = Ar[lane + 64 * m] * inva[k];
    }

    // ---------------- init: M_k = I - (A_k A_k^T)/a_k rows into registers ----
    float mr[KK][32];
#pragma unroll
    for (int k = 0; k < KK; ++k)
#pragma unroll
        for (int cb = 0; cb < 32; ++cb) mr[k][cb] = 0.0f;

#pragma unroll
    for (int k = 0; k < KK; ++k) {
#pragma unroll
        for (int m = 0; m < 8; ++m) Aplds[w][lane + 64 * m] = a2[k][m];
        const float* Ak = A + (size_t)k * MM * NN;
        for (int jc = 0; jc < 128; ++jc) {
            __syncthreads();
#pragma unroll
            for (int cc = 0; cc < 4; ++cc) {
                int c = tid + 512 * cc;
                const float4 v = *(const float4*)(Ak + (size_t)c * NN + jc * 4);
                At[0][c] = v.x; At[1][c] = v.y; At[2][c] = v.z; At[3][c] = v.w;
            }
            __syncthreads();
#pragma unroll
            for (int jj = 0; jj < 4; ++jj) {
                float s = Aplds[w][jc * 4 + jj];   // broadcast
#pragma unroll
                for (int cb = 0; cb < 32; ++cb)
                    mr[k][cb] += s * At[jj][lane + 64 * cb];
            }
        }
        __syncthreads();
    }
#pragma unroll
    for (int k = 0; k < KK; ++k)
#pragma unroll
        for (int cb = 0; cb < 32; ++cb) {
            float d = (lane + 64 * cb == row) ? 1.0f : 0.0f;
            mr[k][cb] = d - mr[k][cb];
        }

    // consumer chunk ownership: thread tid polls chunk tid (all) and
    // chunk 512+tid (tid<256). chunk c -> record c/3, part c%3,
    // h rows [rec*8 + part*3, +3) (part 2 carries only 2 values).
    const int  cA   = tid;
    const int  recA = cA / 3, partA = cA % 3;
    const int  rowA = recA * 8 + partA * 3;
    const bool hasB = (tid < 256);
    const int  cB   = 512 + tid;
    const int  recB = cB / 3, partB = cB % 3;
    const int  rowB = recB * 8 + partB * 3;

    // ---------------- prologue: epoch-0 state straight from inputs ----------
#pragma unroll
    for (int j = 0; j < 4; ++j) lds_h[tid + 512 * j] = h0[tid + 512 * j];
    lds_x[tid] = x[tid];
    __syncthreads();

    // ---------------- sequential scan ----------------
    unsigned int e = 0;   // epoch of the state in lds_h
    for (int t = 0; t < TT; ++t) {
#pragma unroll
        for (int k = 0; k < KK; ++k) {
            // --- compute: v = M_k[row,:] @ h + (A_k[row,:]/a) @ x_t ---
            float p = 0.0f;
#pragma unroll
            for (int m = 0; m < 8; ++m)  p += a2[k][m] * lds_x[lane + 64 * m];
#pragma unroll
            for (int cb = 0; cb < 32; ++cb) p += mr[k][cb] * lds_h[lane + 64 * cb];
#pragma unroll
            for (int s = 1; s < 64; s <<= 1) p += __shfl_xor(p, s, 64);
            float hn = fmaxf(p - rhoa[k], 0.0f);

            // --- publish epoch e+1 ---
            ++e;
            if (lane == 0) {
                lds_hv[w] = hn;
                if (k == KK - 1) out[(size_t)t * MM + row] = hn;
            }
            __syncthreads();   // B1: lds_hv ready; ALL lds_h/lds_x reads done
            if (tid < 3) {
                const int base = tid * 3;
                u32x4 ch;
                ch.x = e;
                ch.y = __float_as_uint(lds_hv[base]);
                ch.z = __float_as_uint(lds_hv[base + 1]);
                ch.w = (tid < 2) ? __float_as_uint(lds_hv[base + 2]) : 0u;
                u32x4* dst = hbuf + (size_t)(e & 1) * NCHUNK + (wg * 3 + tid);
                asm volatile("global_store_dwordx4 %0, %1, off sc0 sc1"
                             :: "v"(dst), "v"(ch) : "memory");
            }
            // stage x_{t+1}: load latency overlaps the poll's remote wait
            if (k == KK - 1 && t + 1 < TT)
                lds_x[tid] = x[(size_t)(t + 1) * NN + tid];

            // --- poll for state e: wave-synchronous free-running rounds ---
            const u32x4* src = hbuf + (size_t)(e & 1) * NCHUNK;
            bool done = false;
            do {
                u32x4 ra, rb;
                if (hasB) {
                    asm volatile(
                        "global_load_dwordx4 %0, %2, off sc0 sc1\n\t"
                        "global_load_dwordx4 %1, %3, off sc0 sc1\n\t"
                        "s_waitcnt vmcnt(0)"
                        : "=v"(ra), "=v"(rb)
                        : "v"(src + cA), "v"(src + cB)
                        : "memory");
                } else {
                    asm volatile(
                        "global_load_dwordx4 %0, %1, off sc0 sc1\n\t"
                        "s_waitcnt vmcnt(0)"
                        : "=v"(ra)
                        : "v"(src + cA)
                        : "memory");
                }
                const bool fA = (ra.x == e);
                const bool fB = hasB ? (rb.x == e) : true;
                if (fA) {                       // idempotent re-write if repeated
                    lds_h[rowA]     = __uint_as_float(ra.y);
                    lds_h[rowA + 1] = __uint_as_float(ra.z);
                    if (partA < 2) lds_h[rowA + 2] = __uint_as_float(ra.w);
                }
                if (fB & hasB) {
                    lds_h[rowB]     = __uint_as_float(rb.y);
                    lds_h[rowB + 1] = __uint_as_float(rb.z);
                    if (partB < 2) lds_h[rowB + 2] = __uint_as_float(rb.w);
                }
                done = __all((int)(fA & fB));   // wave-local, no barrier
            } while (!done);
            __syncthreads();   // B2: all waves' chunks landed in lds_h
        }
    }
}

extern "C" void kernel_launch(void* const* d_in, const int* in_sizes, int n_in,
                              void* d_out, int out_size, void* d_ws, size_t ws_size,
                              hipStream_t stream) {
    const float* x     = (const float*)d_in[0];
    const float* A     = (const float*)d_in[1];
    const float* alpha = (const float*)d_in[2];
    const float* h0    = (const float*)d_in[3];
    float* out = (float*)d_out;
    u32x4* hbuf = (u32x4*)d_ws;   // 2 * 768 * 16B = 24 KB

    hipLaunchKernelGGL(lista_persist, dim3(NWG), dim3(NTHR), 0, stream,
                       x, A, alpha, h0, out, hbuf);
}